// Round 7
// baseline (90.066 us; speedup 1.0000x reference)
//
#include <hip/hip_runtime.h>
#include <hip/hip_bf16.h>
#include <stdint.h>

// RadialAEVComputer: out[b,i,s*16+p] = sum_{j: 0<d<RC, spc(j)=s} exp(-16(d-shf_p)^2)*fc(d)
// B=64, N=256, S=4, P=16, RC=5.2, shf_p = 0.9 + 0.26875*p
// d_in[0]: fp32 [B,256,256] (runtime-fingerprinted, bf16 fallback kept as insurance)
// d_in[1]: int32 [B,256] (1..4); d_out: fp32 [B,256,64]  <-- fp32 OUT (was the bug)
//
// Block = 256 = 4 waves, one wave per row i. Stage (d, fc*mask) in
// wave-private padded LDS; lane=(q,p) accumulates 4 species sums over its
// 64-neighbor quarter; LDS-reduce over q. No ballots / atomics / compaction.

static __device__ __forceinline__ float bf2f(uint32_t b16) {
    union { uint32_t u; float f; } cv; cv.u = b16 << 16; return cv.f;
}

__global__ __launch_bounds__(256) void aev_kernel(
    const void* __restrict__ dmat_raw,   // [B,256,256] fp32 (or bf16 fallback)
    const int* __restrict__ species,     // int32 [B,256], values 1..4
    float* __restrict__ out)             // fp32 [B,256,64]
{
    __shared__ int   spc[272];           // quarter-padded: slot = (j>>6)*68 + (j&63)
    __shared__ float dsh[4][272];        // per-wave row distances (0 if invalid)
    __shared__ float wsh[4][272];        // per-wave fc * mask
    __shared__ float red[4][4][16][4];   // [wave][s][p][q] partials
    __shared__ int   flag32;

    const int tid  = threadIdx.x;
    const int w    = tid >> 6;
    const int lane = tid & 63;
    const int row  = (int)blockIdx.x * 4 + w;   // global row = b*256 + i
    const int b    = row >> 8;

    if (tid == 0) {
        // fp32 fingerprint: d[k][k] == 0.0f exactly for all k. Under bf16 the
        // same word packs (0, d[2k][2k+1] != 0) -> nonzero. 32 bytes, L2-hot.
        const float* f = (const float*)dmat_raw;
        int ok = 1;
        #pragma unroll
        for (int k = 1; k <= 8; ++k) ok &= (f[k * 257] == 0.0f) ? 1 : 0;
        flag32 = ok;
    }
    spc[(tid >> 6) * 68 + (tid & 63)] = species[(b << 8) + tid] - 1;  // 0..3
    __syncthreads();

    // ---- load this wave's row, j = 4*lane + e, per detected dtype ----
    float d[4];
    if (flag32 != 0) {
        const float4* rp = (const float4*)((const float*)dmat_raw + ((size_t)row << 8));
        float4 v = rp[lane];
        d[0] = v.x; d[1] = v.y; d[2] = v.z; d[3] = v.w;
    } else {
        const uint2* rp = (const uint2*)((const uint16_t*)dmat_raw + ((size_t)row << 8));
        uint2 u = rp[lane];
        d[0] = bf2f(u.x & 0xffffu); d[1] = bf2f(u.x >> 16);
        d[2] = bf2f(u.y & 0xffffu); d[3] = bf2f(u.y >> 16);
    }

    {
        const int base = (lane >> 4) * 68 + ((4 * lane) & 63);
        #pragma unroll
        for (int e = 0; e < 4; ++e) {
            float dd = d[e];
            bool  v  = (dd < 5.2f) && (dd != 0.0f);  // false for NaN dd
            float x  = v ? dd : 2.6f;                // cos arg in-domain even if !v
            // fc = 0.5*cos(pi*d/RC)+0.5 ; v_cos takes revolutions: x/(2*RC)
            float fc = 0.5f * __builtin_amdgcn_cosf(x * (0.5f / 5.2f)) + 0.5f;
            dsh[w][base + e] = v ? dd : 0.0f;
            wsh[w][base + e] = v ? fc : 0.0f;
        }
    }
    __syncthreads();

    // ---- accumulate: lane = (q = j-quarter, p = shift) ----
    const int q = lane >> 4;
    const int p = lane & 15;
    const float shfp = 0.9f + 0.26875f * (float)p;
    float a0 = 0.0f, a1 = 0.0f, a2 = 0.0f, a3 = 0.0f;
    const int j0 = q * 68;
    for (int jj = 0; jj < 64; ++jj) {
        float dj = dsh[w][j0 + jj];   // 16-lane broadcast; q-groups on distinct banks
        float wj = wsh[w][j0 + jj];
        int   s  = spc[j0 + jj];
        float u  = dj - shfp;
        // exp(-16*u^2) = exp2(u^2 * -16*log2(e)); arg <= 0, dj/wj always finite
        float t = __builtin_amdgcn_exp2f(u * u * -23.083120654223414f) * wj;
        a0 += (s == 0) ? t : 0.0f;
        a1 += (s == 1) ? t : 0.0f;
        a2 += (s == 2) ? t : 0.0f;
        a3 += (s == 3) ? t : 0.0f;
    }

    red[w][0][p][q] = a0;
    red[w][1][p][q] = a1;
    red[w][2][p][q] = a2;
    red[w][3][p][q] = a3;
    __syncthreads();

    // ---- reduce over q and store fp32: lane < 16 handles shift p = lane ----
    if (lane < 16) {
        const size_t base = ((size_t)row << 6) + (size_t)lane;
        #pragma unroll
        for (int s = 0; s < 4; ++s) {
            float v = red[w][s][lane][0] + red[w][s][lane][1]
                    + red[w][s][lane][2] + red[w][s][lane][3];
            out[base + ((size_t)s << 4)] = v;
        }
    }
}

extern "C" void kernel_launch(void* const* d_in, const int* in_sizes, int n_in,
                              void* d_out, int out_size, void* d_ws, size_t ws_size,
                              hipStream_t stream) {
    const void* dmat   = d_in[0];                        // [B,256,256] fp32
    const int* species = (const int*)d_in[1];            // int32 [B,256]
    float* o           = (float*)d_out;                  // fp32 [B,256,64]
    const int B = in_sizes[1] >> 8;                      // N = 256
    aev_kernel<<<dim3(B * 64), 256, 0, stream>>>(dmat, species, o);
}